// Round 7
// baseline (696.831 us; speedup 1.0000x reference)
//
#include <hip/hip_runtime.h>

// SIGN convolution: h = x @ W + b ; out = segment_sum(adj_vals[:,None] * h[edge_cols], edge_rows)
// Round 7: RPB 128->64; drop bucket_sort (reduce = block-per-bucket LDS accumulator,
// 17.4KB -> 8 blocks/CU, unlike r3's 20%-occupancy version); fuse transpose+hist (prep)
// and gemm||scatter (one launch, block-range split). 5 dispatches total.

#include <stdint.h>

constexpr int KDIM = 256;   // n_in
constexpr int MOUT = 64;    // n_out

constexpr int RPB = 64;         // rows per bucket
constexpr int RPB_SHIFT = 6;
constexpr int MAXBUCK = 2048;   // LDS table capacity (nbuck = 1563 here)
constexpr int CHUNK = 16384;    // edges per scatter block (run length ~8 -> low write-amp)
constexpr int COL_BITS = 20;    // col in low 20 bits, lrow (6b) in bits 20..25
constexpr int COL_MASK = (1 << COL_BITS) - 1;
constexpr int HIST_BLOCKS = 256;

typedef __attribute__((ext_vector_type(8))) short short8v;
typedef __attribute__((ext_vector_type(4))) float f32x4;

__device__ __forceinline__ unsigned short f2bf(float f) {
  unsigned u = __float_as_uint(f);
  return (unsigned short)((u + 0x7fffu + ((u >> 16) & 1u)) >> 16);
}

// ---------------- prep: blocks [0,64) = W transpose->bf16; rest = bucket histogram ----------------
__global__ __launch_bounds__(256)
void prep(const float* __restrict__ W, unsigned short* __restrict__ wt,
          const int* __restrict__ rows, int* __restrict__ bcnt, int E, int nbuck) {
  const int t = threadIdx.x;
  if ((int)blockIdx.x < 64) {
    int n = blockIdx.x;
    wt[n * KDIM + t] = f2bf(W[(size_t)t * MOUT + n]);
    return;
  }
  __shared__ int cnt[MAXBUCK];
  for (int i = t; i < nbuck; i += 256) cnt[i] = 0;
  __syncthreads();
  const int b0 = blockIdx.x - 64;
  for (int e = b0 * 256 + t; e < E; e += HIST_BLOCKS * 256)
    atomicAdd(&cnt[rows[e] >> RPB_SHIFT], 1);
  __syncthreads();
  for (int i = t; i < nbuck; i += 256)
    if (cnt[i]) atomicAdd(&bcnt[i], cnt[i]);
}

// ---------------- scan: single block, multi-chunk exclusive scan (nbuck <= any) ----------------
__global__ __launch_bounds__(1024)
void scan_buckets(const int* __restrict__ bcnt, int* __restrict__ bptr,
                  int* __restrict__ bcur, int nbuck, int E) {
  __shared__ int buf[1024];
  __shared__ int carry;
  const int t = threadIdx.x;
  if (t == 0) carry = 0;
  __syncthreads();
  for (int c0 = 0; c0 < nbuck; c0 += 1024) {
    int i = c0 + t;
    int x = (i < nbuck) ? bcnt[i] : 0;
    buf[t] = x;
    __syncthreads();
    for (int off = 1; off < 1024; off <<= 1) {
      int v = (t >= off) ? buf[t - off] : 0;
      __syncthreads();
      buf[t] += v;
      __syncthreads();
    }
    int incl = buf[t];
    int base = carry;                 // read before update below
    if (i < nbuck) {
      int ex = base + incl - x;
      bptr[i] = ex;
      bcur[i] = ex;
    }
    __syncthreads();
    if (t == 1023) carry = base + incl;
    __syncthreads();
  }
  if (t == 0) bptr[nbuck] = E;
}

// ---------------- fused: blocks [0,gemmBlocks) = MFMA GEMM; rest = bucket scatter ----------------
__global__ __launch_bounds__(256)
void gemm_scatter(const float* __restrict__ x, const unsigned short* __restrict__ wt,
                  const float* __restrict__ bvec, unsigned short* __restrict__ h,
                  const int* __restrict__ rows, const int* __restrict__ cols,
                  const float* __restrict__ vals, int* __restrict__ bcur,
                  int2* __restrict__ sorted, int gemmBlocks, int N, int E, int nbuck) {
  __shared__ __align__(16) char smem[MOUT * 264 * 2];  // 33792B; scatter aliases 16KB of it
  const int t = threadIdx.x;

  if ((int)blockIdx.x < gemmBlocks) {
    auto wlds = reinterpret_cast<unsigned short(*)[264]>(smem);  // 528B rows: 2-way alias only
    for (int i = t; i < MOUT * 32; i += 256) {
      int n = i >> 5, seg = i & 31;
      uint4 v = *reinterpret_cast<const uint4*>(&wt[n * KDIM + seg * 8]);
      *reinterpret_cast<uint4*>(&wlds[n][seg * 8]) = v;
    }
    __syncthreads();

    const int wave = t >> 6, lane = t & 63;
    const int lo = lane & 15, hi = lane >> 4;
    const int rowbase = blockIdx.x * 128 + wave * 32;

    float bias[4];
#pragma unroll
    for (int nt = 0; nt < 4; ++nt) bias[nt] = bvec[nt * 16 + lo];

    f32x4 acc[2][4] = {};

#pragma unroll
    for (int ks = 0; ks < 8; ++ks) {
      short8v bfr[4];
#pragma unroll
      for (int nt = 0; nt < 4; ++nt)
        bfr[nt] = *reinterpret_cast<const short8v*>(&wlds[nt * 16 + lo][ks * 32 + hi * 8]);
#pragma unroll
      for (int mr = 0; mr < 2; ++mr) {
        int r = rowbase + mr * 16 + lo;
        if (r >= N) r = N - 1;  // clamp; stores guarded
        const float* xp = &x[(size_t)r * KDIM + ks * 32 + hi * 8];
        float4 p0 = *reinterpret_cast<const float4*>(xp);
        float4 p1 = *reinterpret_cast<const float4*>(xp + 4);
        short8v a;
        a[0] = (short)f2bf(p0.x); a[1] = (short)f2bf(p0.y);
        a[2] = (short)f2bf(p0.z); a[3] = (short)f2bf(p0.w);
        a[4] = (short)f2bf(p1.x); a[5] = (short)f2bf(p1.y);
        a[6] = (short)f2bf(p1.z); a[7] = (short)f2bf(p1.w);
#pragma unroll
        for (int nt = 0; nt < 4; ++nt)
          acc[mr][nt] = __builtin_amdgcn_mfma_f32_16x16x32_bf16(a, bfr[nt], acc[mr][nt], 0, 0, 0);
      }
    }

#pragma unroll
    for (int mr = 0; mr < 2; ++mr)
#pragma unroll
      for (int reg = 0; reg < 4; ++reg) {
        int row = rowbase + mr * 16 + hi * 4 + reg;
        if (row < N) {
#pragma unroll
          for (int nt = 0; nt < 4; ++nt)
            h[(size_t)row * MOUT + nt * 16 + lo] = f2bf(acc[mr][nt][reg] + bias[nt]);
        }
      }
    return;
  }

  // ---- scatter role ----
  int* lcnt  = reinterpret_cast<int*>(smem);
  int* lbase = lcnt + MAXBUCK;
  const int cid = blockIdx.x - gemmBlocks;
  const int e0 = cid * CHUNK;
  const int e1 = min(e0 + CHUNK, E);

  for (int i = t; i < nbuck; i += 256) lcnt[i] = 0;
  __syncthreads();
  for (int e = e0 + t; e < e1; e += 256)
    atomicAdd(&lcnt[rows[e] >> RPB_SHIFT], 1);
  __syncthreads();
  for (int i = t; i < nbuck; i += 256) {
    int c = lcnt[i];
    lbase[i] = c ? atomicAdd(&bcur[i], c) : 0;
  }
  __syncthreads();
  for (int i = t; i < nbuck; i += 256) lcnt[i] = 0;
  __syncthreads();
  for (int e = e0 + t; e < e1; e += 256) {
    int r = rows[e];
    int b = r >> RPB_SHIFT;
    int lrow = r & (RPB - 1);
    int pos = lbase[b] + atomicAdd(&lcnt[b], 1);
    sorted[pos] = make_int2((lrow << COL_BITS) | cols[e], __float_as_int(vals[e]));
  }
}

// ---------------- reduce: one block per 64-row bucket, LDS f32 accumulator ----------------
// 256 thr = 32 edge-slots x 8 parts (16B of the 128B h row). +4 pad floats/row:
// stride 68 -> bank=(lrow*4+col)%32, random lrow spreads ds_add across banks.
__global__ __launch_bounds__(256)
void reduce64(const unsigned short* __restrict__ h, const int2* __restrict__ sorted,
              const int* __restrict__ bptr, float* __restrict__ out, int N) {
  __shared__ float acc[RPB][MOUT + 4];  // 17408 B -> 8 blocks/CU
  const int t = threadIdx.x;
  const int b = blockIdx.x;
  float* af = &acc[0][0];
  for (int i = t; i < RPB * (MOUT + 4); i += 256) af[i] = 0.f;
  __syncthreads();

  const int slot = t >> 3;   // 32 edges per round
  const int part = t & 7;
  const int s = bptr[b];
  const int e = bptr[b + 1];

  int j = s + slot;
  for (; j + 32 < e; j += 64) {  // 2x unroll: both gathers in flight before ds ops
    int2 p0 = sorted[j];
    int2 p1 = sorted[j + 32];
    float v0 = __int_as_float(p0.y);
    float v1 = __int_as_float(p1.y);
    uint4 h0 = *reinterpret_cast<const uint4*>(&h[(size_t)(p0.x & COL_MASK) * MOUT + part * 8]);
    uint4 h1 = *reinterpret_cast<const uint4*>(&h[(size_t)(p1.x & COL_MASK) * MOUT + part * 8]);
    float* a0 = &acc[p0.x >> COL_BITS][part * 8];
    float* a1 = &acc[p1.x >> COL_BITS][part * 8];
    atomicAdd(a0 + 0, v0 * __uint_as_float(h0.x << 16));
    atomicAdd(a0 + 1, v0 * __uint_as_float(h0.x & 0xffff0000u));
    atomicAdd(a0 + 2, v0 * __uint_as_float(h0.y << 16));
    atomicAdd(a0 + 3, v0 * __uint_as_float(h0.y & 0xffff0000u));
    atomicAdd(a0 + 4, v0 * __uint_as_float(h0.z << 16));
    atomicAdd(a0 + 5, v0 * __uint_as_float(h0.z & 0xffff0000u));
    atomicAdd(a0 + 6, v0 * __uint_as_float(h0.w << 16));
    atomicAdd(a0 + 7, v0 * __uint_as_float(h0.w & 0xffff0000u));
    atomicAdd(a1 + 0, v1 * __uint_as_float(h1.x << 16));
    atomicAdd(a1 + 1, v1 * __uint_as_float(h1.x & 0xffff0000u));
    atomicAdd(a1 + 2, v1 * __uint_as_float(h1.y << 16));
    atomicAdd(a1 + 3, v1 * __uint_as_float(h1.y & 0xffff0000u));
    atomicAdd(a1 + 4, v1 * __uint_as_float(h1.z << 16));
    atomicAdd(a1 + 5, v1 * __uint_as_float(h1.z & 0xffff0000u));
    atomicAdd(a1 + 6, v1 * __uint_as_float(h1.w << 16));
    atomicAdd(a1 + 7, v1 * __uint_as_float(h1.w & 0xffff0000u));
  }
  for (; j < e; j += 32) {
    int2 p = sorted[j];
    float v = __int_as_float(p.y);
    uint4 hv = *reinterpret_cast<const uint4*>(&h[(size_t)(p.x & COL_MASK) * MOUT + part * 8]);
    float* a = &acc[p.x >> COL_BITS][part * 8];
    atomicAdd(a + 0, v * __uint_as_float(hv.x << 16));
    atomicAdd(a + 1, v * __uint_as_float(hv.x & 0xffff0000u));
    atomicAdd(a + 2, v * __uint_as_float(hv.y << 16));
    atomicAdd(a + 3, v * __uint_as_float(hv.y & 0xffff0000u));
    atomicAdd(a + 4, v * __uint_as_float(hv.z << 16));
    atomicAdd(a + 5, v * __uint_as_float(hv.z & 0xffff0000u));
    atomicAdd(a + 6, v * __uint_as_float(hv.w << 16));
    atomicAdd(a + 7, v * __uint_as_float(hv.w & 0xffff0000u));
  }
  __syncthreads();

  const int row0 = b * RPB;
  for (int i = t; i < RPB * (MOUT / 4); i += 256) {  // 1024 float4 stores
    int lr = i >> 4, c4 = i & 15;
    int grow = row0 + lr;
    if (grow < N) {
      float4 o = make_float4(acc[lr][c4 * 4], acc[lr][c4 * 4 + 1],
                             acc[lr][c4 * 4 + 2], acc[lr][c4 * 4 + 3]);
      *reinterpret_cast<float4*>(&out[(size_t)grow * MOUT + c4 * 4]) = o;
    }
  }
}

// ---------------- Fallback path (ws too small): wt + gemm + f32-atomic scatter ----------------
__global__ __launch_bounds__(256)
void wt_transpose(const float* __restrict__ W, unsigned short* __restrict__ wt) {
  int n = blockIdx.x;
  int k = threadIdx.x;
  wt[n * KDIM + k] = f2bf(W[(size_t)k * MOUT + n]);
}

__global__ __launch_bounds__(256)
void scatter_edges(const unsigned short* __restrict__ h, const float* __restrict__ vals,
                   const int* __restrict__ rows, const int* __restrict__ cols,
                   float* __restrict__ out, int E) {
  long long idx = (long long)blockIdx.x * blockDim.x + threadIdx.x;
  int e = (int)(idx >> 4);
  int part = (int)(idx & 15);
  if (e >= E) return;
  int r = rows[e];
  int c = cols[e];
  float v = vals[e];
  uint2 hv = *reinterpret_cast<const uint2*>(&h[(size_t)c * MOUT + part * 4]);
  float* op = &out[(size_t)r * MOUT + part * 4];
  atomicAdd(op + 0, v * __uint_as_float(hv.x << 16));
  atomicAdd(op + 1, v * __uint_as_float(hv.x & 0xffff0000u));
  atomicAdd(op + 2, v * __uint_as_float(hv.y << 16));
  atomicAdd(op + 3, v * __uint_as_float(hv.y & 0xffff0000u));
}

static inline size_t align256(size_t x) { return (x + 255) & ~(size_t)255; }

extern "C" void kernel_launch(void* const* d_in, const int* in_sizes, int n_in,
                              void* d_out, int out_size, void* d_ws, size_t ws_size,
                              hipStream_t stream) {
  const float* x    = (const float*)d_in[0];
  const float* W    = (const float*)d_in[1];
  const float* bvec = (const float*)d_in[2];
  const float* vals = (const float*)d_in[3];
  const int* erows  = (const int*)d_in[4];
  const int* ecols  = (const int*)d_in[5];
  float* out = (float*)d_out;

  const int N = in_sizes[0] / KDIM;   // 100000
  const int E = in_sizes[3];          // 1600000
  const int nbuck = (N + RPB - 1) / RPB;  // 1563

  // workspace layout (~25.7 MB)
  char* ws = (char*)d_ws;
  size_t off_h  = 0;                                                    // h bf16 [N][64]
  size_t off_wt = align256(off_h + (size_t)N * MOUT * sizeof(short));   // wt bf16 [64][256]
  size_t off_bp = align256(off_wt + (size_t)MOUT * KDIM * sizeof(short));
  size_t off_bc = align256(off_bp + (size_t)(nbuck + 1) * sizeof(int));
  size_t off_cu = align256(off_bc + (size_t)nbuck * sizeof(int));
  size_t off_sp = align256(off_cu + (size_t)nbuck * sizeof(int));
  size_t need   = off_sp + (size_t)E * sizeof(int2);

  unsigned short* h  = (unsigned short*)(ws + off_h);
  unsigned short* wt = (unsigned short*)(ws + off_wt);

  dim3 blk256(256);
  const int gemmBlocks = (N + 127) / 128;

  if (ws_size >= need && nbuck <= MAXBUCK && N < (1 << COL_BITS)) {
    int* bptr = (int*)(ws + off_bp);
    int* bcnt = (int*)(ws + off_bc);
    int* bcur = (int*)(ws + off_cu);
    int2* sorted = (int2*)(ws + off_sp);

    hipMemsetAsync(bcnt, 0, (size_t)nbuck * sizeof(int), stream);
    prep<<<dim3(64 + HIST_BLOCKS), blk256, 0, stream>>>(W, wt, erows, bcnt, E, nbuck);
    scan_buckets<<<dim3(1), dim3(1024), 0, stream>>>(bcnt, bptr, bcur, nbuck, E);
    const int scatBlocks = (E + CHUNK - 1) / CHUNK;
    gemm_scatter<<<dim3(gemmBlocks + scatBlocks), blk256, 0, stream>>>(
        x, wt, bvec, h, erows, ecols, vals, bcur, sorted, gemmBlocks, N, E, nbuck);
    reduce64<<<dim3(nbuck), blk256, 0, stream>>>(h, sorted, bptr, out, N);
  } else {
    wt_transpose<<<dim3(MOUT), blk256, 0, stream>>>(W, wt);
    // gemm-only: grid exactly gemmBlocks -> scatter role never taken; dummy ptrs unused
    gemm_scatter<<<dim3(gemmBlocks), blk256, 0, stream>>>(
        x, wt, bvec, h, erows, ecols, vals, (int*)wt, (int2*)h, gemmBlocks, N, E, nbuck);
    hipMemsetAsync(d_out, 0, (size_t)out_size * sizeof(float), stream);
    long long work = (long long)E * 16;
    scatter_edges<<<dim3((unsigned)((work + 255) / 256)), blk256, 0, stream>>>(h, vals, erows, ecols, out, E);
  }
}

// Round 8
// 127.877 us; speedup vs baseline: 5.4492x; 5.4492x over previous
//
#include <hip/hip_runtime.h>

// SIGN convolution: h = x @ W + b ; out = segment_sum(adj_vals[:,None] * h[edge_cols], edge_rows)
// Round 8: revert r7's LDS-atomic reduce (604us: LDS-atomic-throughput bound, same-addr
// serialization). Restore r6's bucket_sort + one-wave-per-row reduce (144.5us baseline),
// KEEP r7's sound fusions: prep = transpose||hist, gemm_scatter = gemm||scatter.

#include <stdint.h>

constexpr int KDIM = 256;   // n_in
constexpr int MOUT = 64;    // n_out

constexpr int RPB = 128;        // rows per bucket
constexpr int RPB_SHIFT = 7;
constexpr int MAXBUCK = 1024;   // LDS table capacity (nbuck = 782 here)
constexpr int CHUNK = 8192;     // edges per scatter block
constexpr int COL_BITS = 20;    // col in low 20 bits, lrow (7b) in bits 20..26
constexpr int COL_MASK = (1 << COL_BITS) - 1;
constexpr int SORT_CAP = 6144;  // 48KB LDS stage; mean bucket = 2046 here
constexpr int HIST_BLOCKS = 256;

typedef __attribute__((ext_vector_type(8))) short short8v;
typedef __attribute__((ext_vector_type(4))) float f32x4;

__device__ __forceinline__ unsigned short f2bf(float f) {
  unsigned u = __float_as_uint(f);
  return (unsigned short)((u + 0x7fffu + ((u >> 16) & 1u)) >> 16);
}

// ---------------- prep: blocks [0,64) = W transpose->bf16; rest = bucket histogram ----------------
__global__ __launch_bounds__(256)
void prep(const float* __restrict__ W, unsigned short* __restrict__ wt,
          const int* __restrict__ rows, int* __restrict__ bcnt, int E, int nbuck) {
  const int t = threadIdx.x;
  if ((int)blockIdx.x < 64) {
    int n = blockIdx.x;
    wt[n * KDIM + t] = f2bf(W[(size_t)t * MOUT + n]);
    return;
  }
  __shared__ int cnt[MAXBUCK];
  for (int i = t; i < nbuck; i += 256) cnt[i] = 0;
  __syncthreads();
  const int b0 = blockIdx.x - 64;
  for (int e = b0 * 256 + t; e < E; e += HIST_BLOCKS * 256)
    atomicAdd(&cnt[rows[e] >> RPB_SHIFT], 1);
  __syncthreads();
  for (int i = t; i < nbuck; i += 256)
    if (cnt[i]) atomicAdd(&bcnt[i], cnt[i]);
}

// ---------------- scan: single block, multi-chunk exclusive scan ----------------
__global__ __launch_bounds__(1024)
void scan_buckets(const int* __restrict__ bcnt, int* __restrict__ bptr,
                  int* __restrict__ bcur, int nbuck, int E) {
  __shared__ int buf[1024];
  __shared__ int carry;
  const int t = threadIdx.x;
  if (t == 0) carry = 0;
  __syncthreads();
  for (int c0 = 0; c0 < nbuck; c0 += 1024) {
    int i = c0 + t;
    int x = (i < nbuck) ? bcnt[i] : 0;
    buf[t] = x;
    __syncthreads();
    for (int off = 1; off < 1024; off <<= 1) {
      int v = (t >= off) ? buf[t - off] : 0;
      __syncthreads();
      buf[t] += v;
      __syncthreads();
    }
    int incl = buf[t];
    int base = carry;
    if (i < nbuck) {
      int ex = base + incl - x;
      bptr[i] = ex;
      bcur[i] = ex;
    }
    __syncthreads();
    if (t == 1023) carry = base + incl;
    __syncthreads();
  }
  if (t == 0) bptr[nbuck] = E;
}

// ---------------- fused: blocks [0,gemmBlocks) = MFMA GEMM; rest = bucket scatter ----------------
__global__ __launch_bounds__(256)
void gemm_scatter(const float* __restrict__ x, const unsigned short* __restrict__ wt,
                  const float* __restrict__ bvec, unsigned short* __restrict__ h,
                  const int* __restrict__ rows, const int* __restrict__ cols,
                  const float* __restrict__ vals, int* __restrict__ bcur,
                  int2* __restrict__ sorted, int gemmBlocks, int N, int E, int nbuck) {
  __shared__ __align__(16) char smem[MOUT * 264 * 2];  // 33792B; scatter aliases 8KB
  const int t = threadIdx.x;

  if ((int)blockIdx.x < gemmBlocks) {
    auto wlds = reinterpret_cast<unsigned short(*)[264]>(smem);  // 528B rows: 2-way alias only
    for (int i = t; i < MOUT * 32; i += 256) {
      int n = i >> 5, seg = i & 31;
      uint4 v = *reinterpret_cast<const uint4*>(&wt[n * KDIM + seg * 8]);
      *reinterpret_cast<uint4*>(&wlds[n][seg * 8]) = v;
    }
    __syncthreads();

    const int wave = t >> 6, lane = t & 63;
    const int lo = lane & 15, hi = lane >> 4;
    const int rowbase = blockIdx.x * 128 + wave * 32;

    float bias[4];
#pragma unroll
    for (int nt = 0; nt < 4; ++nt) bias[nt] = bvec[nt * 16 + lo];

    f32x4 acc[2][4] = {};

#pragma unroll
    for (int ks = 0; ks < 8; ++ks) {
      short8v bfr[4];
#pragma unroll
      for (int nt = 0; nt < 4; ++nt)
        bfr[nt] = *reinterpret_cast<const short8v*>(&wlds[nt * 16 + lo][ks * 32 + hi * 8]);
#pragma unroll
      for (int mr = 0; mr < 2; ++mr) {
        int r = rowbase + mr * 16 + lo;
        if (r >= N) r = N - 1;  // clamp; stores guarded
        const float* xp = &x[(size_t)r * KDIM + ks * 32 + hi * 8];
        float4 p0 = *reinterpret_cast<const float4*>(xp);
        float4 p1 = *reinterpret_cast<const float4*>(xp + 4);
        short8v a;
        a[0] = (short)f2bf(p0.x); a[1] = (short)f2bf(p0.y);
        a[2] = (short)f2bf(p0.z); a[3] = (short)f2bf(p0.w);
        a[4] = (short)f2bf(p1.x); a[5] = (short)f2bf(p1.y);
        a[6] = (short)f2bf(p1.z); a[7] = (short)f2bf(p1.w);
#pragma unroll
        for (int nt = 0; nt < 4; ++nt)
          acc[mr][nt] = __builtin_amdgcn_mfma_f32_16x16x32_bf16(a, bfr[nt], acc[mr][nt], 0, 0, 0);
      }
    }

#pragma unroll
    for (int mr = 0; mr < 2; ++mr)
#pragma unroll
      for (int reg = 0; reg < 4; ++reg) {
        int row = rowbase + mr * 16 + hi * 4 + reg;
        if (row < N) {
#pragma unroll
          for (int nt = 0; nt < 4; ++nt)
            h[(size_t)row * MOUT + nt * 16 + lo] = f2bf(acc[mr][nt][reg] + bias[nt]);
        }
      }
    return;
  }

  // ---- scatter role ----
  int* lcnt  = reinterpret_cast<int*>(smem);
  int* lbase = lcnt + MAXBUCK;
  const int cid = blockIdx.x - gemmBlocks;
  const int e0 = cid * CHUNK;
  const int e1 = min(e0 + CHUNK, E);

  for (int i = t; i < nbuck; i += 256) lcnt[i] = 0;
  __syncthreads();
  for (int e = e0 + t; e < e1; e += 256)
    atomicAdd(&lcnt[rows[e] >> RPB_SHIFT], 1);
  __syncthreads();
  for (int i = t; i < nbuck; i += 256) {
    int c = lcnt[i];
    lbase[i] = c ? atomicAdd(&bcur[i], c) : 0;
  }
  __syncthreads();
  for (int i = t; i < nbuck; i += 256) lcnt[i] = 0;
  __syncthreads();
  for (int e = e0 + t; e < e1; e += 256) {
    int r = rows[e];
    int b = r >> RPB_SHIFT;
    int lrow = r & (RPB - 1);
    int pos = lbase[b] + atomicAdd(&lcnt[b], 1);
    sorted[pos] = make_int2((lrow << COL_BITS) | cols[e], __float_as_int(vals[e]));
  }
}

// ---------------- per-bucket in-LDS counting sort + row_ptr ----------------
__global__ __launch_bounds__(256)
void bucket_sort(int2* __restrict__ sorted, const int* __restrict__ bptr,
                 int* __restrict__ row_ptr, int* __restrict__ bflag,
                 int N, int E, int nbuck) {
  __shared__ int2 eds[SORT_CAP];   // 48 KB
  __shared__ int lcnt[RPB];
  __shared__ int loff[RPB];
  __shared__ int lcur[RPB];
  const int t = threadIdx.x;
  const int b = blockIdx.x;
  const int s = bptr[b];
  const int e = bptr[b + 1];
  const int cnt = e - s;
  const int row0 = b << RPB_SHIFT;

  if (b == 0 && t == 0) row_ptr[N] = E;

  if (cnt > SORT_CAP) {  // correctness fallback
    if (t == 0) bflag[b] = 1;
    if (t < RPB && row0 + t < N) row_ptr[row0 + t] = s;
    return;
  }
  if (t == 0) bflag[b] = 0;

  if (t < RPB) lcnt[t] = 0;
  __syncthreads();
  for (int j = s + t; j < e; j += 256) {
    int2 p = sorted[j];
    eds[j - s] = p;
    atomicAdd(&lcnt[p.x >> COL_BITS], 1);
  }
  __syncthreads();
  if (t < RPB) loff[t] = lcnt[t];
  __syncthreads();
  for (int off = 1; off < RPB; off <<= 1) {
    int v = (t < RPB && t >= off) ? loff[t - off] : 0;
    __syncthreads();
    if (t < RPB) loff[t] += v;
    __syncthreads();
  }
  if (t < RPB) {
    int ex = loff[t] - lcnt[t];
    loff[t] = ex;
    lcur[t] = 0;
    int grow = row0 + t;
    if (grow < N) row_ptr[grow] = s + ex;
  }
  __syncthreads();
  for (int idx = t; idx < cnt; idx += 256) {
    int2 p = eds[idx];
    int lr = p.x >> COL_BITS;
    int pos = s + loff[lr] + atomicAdd(&lcur[lr], 1);
    sorted[pos] = p;
  }
}

// ---------------- reduce: one wave per row, 8 slots x 8 parts, 2x unroll ----------------
__device__ __forceinline__ void edge_fma(float* acc, const unsigned short* h,
                                         int2 p, int part) {
  float v = __int_as_float(p.y);
  int col = p.x & COL_MASK;
  uint4 hv = *reinterpret_cast<const uint4*>(&h[(size_t)col * MOUT + part * 8]);
  acc[0] += v * __uint_as_float(hv.x << 16);
  acc[1] += v * __uint_as_float(hv.x & 0xffff0000u);
  acc[2] += v * __uint_as_float(hv.y << 16);
  acc[3] += v * __uint_as_float(hv.y & 0xffff0000u);
  acc[4] += v * __uint_as_float(hv.z << 16);
  acc[5] += v * __uint_as_float(hv.z & 0xffff0000u);
  acc[6] += v * __uint_as_float(hv.w << 16);
  acc[7] += v * __uint_as_float(hv.w & 0xffff0000u);
}

__global__ __launch_bounds__(256)
void reduce_rows(const unsigned short* __restrict__ h, const int2* __restrict__ sorted,
                 const int* __restrict__ row_ptr, const int* __restrict__ bptr,
                 const int* __restrict__ bflag, float* __restrict__ out, int N) {
  int row = (blockIdx.x * 256 + threadIdx.x) >> 6;
  if (row >= N) return;
  int lane = threadIdx.x & 63;
  int slot = lane >> 3;   // 8 edge slots
  int part = lane & 7;    // 16B (8 bf16) of the 128B h row
  int b = row >> RPB_SHIFT;
  int lrow = row & (RPB - 1);
  bool filt = bflag[b] != 0;

  float acc[8];
#pragma unroll
  for (int i = 0; i < 8; ++i) acc[i] = 0.f;

  if (!filt) {
    int s = row_ptr[row];
    int e = row_ptr[row + 1];
    int j = s + slot;
    for (; j + 8 < e; j += 16) {
      int2 p0 = sorted[j];
      int2 p1 = sorted[j + 8];
      float v0 = __int_as_float(p0.y);
      float v1 = __int_as_float(p1.y);
      uint4 h0 = *reinterpret_cast<const uint4*>(
          &h[(size_t)(p0.x & COL_MASK) * MOUT + part * 8]);
      uint4 h1 = *reinterpret_cast<const uint4*>(
          &h[(size_t)(p1.x & COL_MASK) * MOUT + part * 8]);
      acc[0] += v0 * __uint_as_float(h0.x << 16);
      acc[1] += v0 * __uint_as_float(h0.x & 0xffff0000u);
      acc[2] += v0 * __uint_as_float(h0.y << 16);
      acc[3] += v0 * __uint_as_float(h0.y & 0xffff0000u);
      acc[4] += v0 * __uint_as_float(h0.z << 16);
      acc[5] += v0 * __uint_as_float(h0.z & 0xffff0000u);
      acc[6] += v0 * __uint_as_float(h0.w << 16);
      acc[7] += v0 * __uint_as_float(h0.w & 0xffff0000u);
      acc[0] += v1 * __uint_as_float(h1.x << 16);
      acc[1] += v1 * __uint_as_float(h1.x & 0xffff0000u);
      acc[2] += v1 * __uint_as_float(h1.y << 16);
      acc[3] += v1 * __uint_as_float(h1.y & 0xffff0000u);
      acc[4] += v1 * __uint_as_float(h1.z << 16);
      acc[5] += v1 * __uint_as_float(h1.z & 0xffff0000u);
      acc[6] += v1 * __uint_as_float(h1.w << 16);
      acc[7] += v1 * __uint_as_float(h1.w & 0xffff0000u);
    }
    if (j < e) edge_fma(acc, h, sorted[j], part);
  } else {
    int s = bptr[b];
    int e = bptr[b + 1];
    for (int j = s + slot; j < e; j += 8) {
      int2 p = sorted[j];
      if ((p.x >> COL_BITS) != lrow) continue;
      edge_fma(acc, h, p, part);
    }
  }

#pragma unroll
  for (int m = 8; m <= 32; m <<= 1)
#pragma unroll
    for (int i = 0; i < 8; ++i)
      acc[i] += __shfl_xor(acc[i], m, 64);

  if (slot == 0) {
    float* op = &out[(size_t)row * MOUT + part * 8];
    *reinterpret_cast<float4*>(op)     = make_float4(acc[0], acc[1], acc[2], acc[3]);
    *reinterpret_cast<float4*>(op + 4) = make_float4(acc[4], acc[5], acc[6], acc[7]);
  }
}

// ---------------- Fallback path (ws too small): f32-atomic scatter ----------------
__global__ __launch_bounds__(256)
void scatter_edges(const unsigned short* __restrict__ h, const float* __restrict__ vals,
                   const int* __restrict__ rows, const int* __restrict__ cols,
                   float* __restrict__ out, int E) {
  long long idx = (long long)blockIdx.x * blockDim.x + threadIdx.x;
  int e = (int)(idx >> 4);
  int part = (int)(idx & 15);
  if (e >= E) return;
  int r = rows[e];
  int c = cols[e];
  float v = vals[e];
  uint2 hv = *reinterpret_cast<const uint2*>(&h[(size_t)c * MOUT + part * 4]);
  float* op = &out[(size_t)r * MOUT + part * 4];
  atomicAdd(op + 0, v * __uint_as_float(hv.x << 16));
  atomicAdd(op + 1, v * __uint_as_float(hv.x & 0xffff0000u));
  atomicAdd(op + 2, v * __uint_as_float(hv.y << 16));
  atomicAdd(op + 3, v * __uint_as_float(hv.y & 0xffff0000u));
}

__global__ __launch_bounds__(256)
void wt_transpose(const float* __restrict__ W, unsigned short* __restrict__ wt) {
  int n = blockIdx.x;
  int k = threadIdx.x;
  wt[n * KDIM + k] = f2bf(W[(size_t)k * MOUT + n]);
}

static inline size_t align256(size_t x) { return (x + 255) & ~(size_t)255; }

extern "C" void kernel_launch(void* const* d_in, const int* in_sizes, int n_in,
                              void* d_out, int out_size, void* d_ws, size_t ws_size,
                              hipStream_t stream) {
  const float* x    = (const float*)d_in[0];
  const float* W    = (const float*)d_in[1];
  const float* bvec = (const float*)d_in[2];
  const float* vals = (const float*)d_in[3];
  const int* erows  = (const int*)d_in[4];
  const int* ecols  = (const int*)d_in[5];
  float* out = (float*)d_out;

  const int N = in_sizes[0] / KDIM;   // 100000
  const int E = in_sizes[3];          // 1600000
  const int nbuck = (N + RPB - 1) / RPB;  // 782

  // workspace layout (~26 MB)
  char* ws = (char*)d_ws;
  size_t off_h  = 0;                                                    // h bf16 [N][64]
  size_t off_wt = align256(off_h + (size_t)N * MOUT * sizeof(short));   // wt bf16 [64][256]
  size_t off_bp = align256(off_wt + (size_t)MOUT * KDIM * sizeof(short));
  size_t off_bc = align256(off_bp + (size_t)(nbuck + 1) * sizeof(int));
  size_t off_cu = align256(off_bc + (size_t)nbuck * sizeof(int));
  size_t off_bf = align256(off_cu + (size_t)nbuck * sizeof(int));
  size_t off_rp = align256(off_bf + (size_t)nbuck * sizeof(int));
  size_t off_sp = align256(off_rp + (size_t)(N + 1) * sizeof(int));
  size_t need   = off_sp + (size_t)E * sizeof(int2);

  unsigned short* h  = (unsigned short*)(ws + off_h);
  unsigned short* wt = (unsigned short*)(ws + off_wt);

  dim3 blk256(256);
  const int gemmBlocks = (N + 127) / 128;

  if (ws_size >= need && nbuck <= MAXBUCK && N < (1 << COL_BITS)) {
    int* bptr  = (int*)(ws + off_bp);
    int* bcnt  = (int*)(ws + off_bc);
    int* bcur  = (int*)(ws + off_cu);
    int* bflag = (int*)(ws + off_bf);
    int* row_ptr = (int*)(ws + off_rp);
    int2* sorted = (int2*)(ws + off_sp);

    hipMemsetAsync(bcnt, 0, (size_t)nbuck * sizeof(int), stream);
    prep<<<dim3(64 + HIST_BLOCKS), blk256, 0, stream>>>(W, wt, erows, bcnt, E, nbuck);
    scan_buckets<<<dim3(1), dim3(1024), 0, stream>>>(bcnt, bptr, bcur, nbuck, E);
    const int scatBlocks = (E + CHUNK - 1) / CHUNK;
    gemm_scatter<<<dim3(gemmBlocks + scatBlocks), blk256, 0, stream>>>(
        x, wt, bvec, h, erows, ecols, vals, bcur, sorted, gemmBlocks, N, E, nbuck);
    bucket_sort<<<dim3(nbuck), blk256, 0, stream>>>(sorted, bptr, row_ptr, bflag, N, E, nbuck);
    reduce_rows<<<dim3(((size_t)N * 64 + 255) / 256), blk256, 0, stream>>>(
        h, sorted, row_ptr, bptr, bflag, out, N);
  } else {
    wt_transpose<<<dim3(MOUT), blk256, 0, stream>>>(W, wt);
    gemm_scatter<<<dim3(gemmBlocks), blk256, 0, stream>>>(
        x, wt, bvec, h, erows, ecols, vals, (int*)wt, (int2*)h, gemmBlocks, N, E, nbuck);
    hipMemsetAsync(d_out, 0, (size_t)out_size * sizeof(float), stream);
    long long work = (long long)E * 16;
    scatter_edges<<<dim3((unsigned)((work + 255) / 256)), blk256, 0, stream>>>(h, vals, erows, ecols, out, E);
  }
}